// Round 1
// baseline (727.148 us; speedup 1.0000x reference)
//
#include <hip/hip_runtime.h>
#include <math.h>

#define T_SEQ 2048
#define BATCH 4
#define DMODEL 128
#define DFF 512
#define NHEAD 8
#define EHEAD 16

// 1/sqrt(2048)
#define RSQRT_T 0.022097086912079608f

// ---------------------------------------------------------------------------
// K1: xpe = x + positional_encoding
// ---------------------------------------------------------------------------
__global__ __launch_bounds__(256) void k_pe(const float* __restrict__ x,
                                            float* __restrict__ xpe) {
    int idx = blockIdx.x * 256 + threadIdx.x;       // over B*T*D = 1M
    int f = idx & (DMODEL - 1);
    int t = (idx >> 7) & (T_SEQ - 1);
    // div = exp(-(f&~1) * ln(10000)/d)
    float dv = __expf(-(float)(f & ~1) * (9.210340371976184f / 128.0f));
    float ang = (float)t * dv;
    float pe = (f & 1) ? cosf(ang) : sinf(ang);
    xpe[idx] = x[idx] + pe;
}

// ---------------------------------------------------------------------------
// K2: generic tiled GEMM  C[M x N] = A[M x KD] @ W[KD x N]  (+bias)(relu)(+res)
// block = 256 threads handles 16 rows x 128 cols; grid = (M/16, N/128)
// ---------------------------------------------------------------------------
template <int KD, int N, bool RELU>
__global__ __launch_bounds__(256) void k_gemm(const float* __restrict__ A,
                                              const float* __restrict__ W,
                                              const float* __restrict__ bias,
                                              const float* __restrict__ res,
                                              float* __restrict__ C) {
    __shared__ float At[16][KD + 1];
    int row0 = blockIdx.x * 16;
    int colBase = blockIdx.y * 128;
    for (int idx = threadIdx.x; idx < 16 * KD; idx += 256) {
        int r = idx / KD, k = idx % KD;
        At[r][k] = A[(size_t)(row0 + r) * KD + k];
    }
    __syncthreads();
    int col = colBase + (threadIdx.x & 127);
    int rg = (threadIdx.x >> 7) * 8;
    float acc[8];
#pragma unroll
    for (int r = 0; r < 8; ++r) acc[r] = 0.f;
    for (int k = 0; k < KD; ++k) {
        float w = W[(size_t)k * N + col];
#pragma unroll
        for (int r = 0; r < 8; ++r) acc[r] += At[rg + r][k] * w;
    }
    float b = bias ? bias[col] : 0.f;
#pragma unroll
    for (int r = 0; r < 8; ++r) {
        float v = acc[r] + b;
        if (RELU) v = fmaxf(v, 0.f);
        int row = row0 + rg + r;
        if (res) v += res[(size_t)row * N + col];
        C[(size_t)row * N + col] = v;
    }
}

// ---------------------------------------------------------------------------
// K3: column-softmax denominators.
// invc[h,b,k] = 1 / sum_{q>=k} exp(S[q,k]),  S[q,k] = dot16(Q[q],K[k]) / sqrt(T)
// grid = (T/256, H*B), block = 256 (one thread per column k)
// ---------------------------------------------------------------------------
__global__ __launch_bounds__(256) void k_colsum(const float* __restrict__ Qm,
                                                const float* __restrict__ Km,
                                                float* __restrict__ invc) {
    int hb = blockIdx.y;
    int h = hb >> 2;          // B = 4
    int b = hb & 3;
    int k0 = blockIdx.x * 256;
    int kcol = k0 + threadIdx.x;
    size_t base = (size_t)b * T_SEQ;

    float kreg[EHEAD];
    const float* Kp = Km + (base + kcol) * DMODEL + h * EHEAD;
#pragma unroll
    for (int e = 0; e < EHEAD; ++e) kreg[e] = Kp[e];

    __shared__ float Qt[128][EHEAD];
    float c = 0.f;
    for (int q0 = k0; q0 < T_SEQ; q0 += 128) {
        for (int idx = threadIdx.x; idx < 128 * EHEAD; idx += 256) {
            int r = idx >> 4, e = idx & 15;
            Qt[r][e] = Qm[(base + q0 + r) * DMODEL + h * EHEAD + e];
        }
        __syncthreads();
        int qqstart = (kcol > q0) ? (kcol - q0) : 0;
        for (int qq = qqstart; qq < 128; ++qq) {
            float s = 0.f;
#pragma unroll
            for (int e = 0; e < EHEAD; ++e) s += Qt[qq][e] * kreg[e];
            c += __expf(s * RSQRT_T);
        }
        __syncthreads();
    }
    invc[(size_t)hb * T_SEQ + kcol] = 1.0f / c;
}

// ---------------------------------------------------------------------------
// K4: attention output.
// AO[b,q,h*16+e] = sum_{k<=q} exp(S[q,k])*invc[k] * V[k,e]
// grid = (T/16, H*B), block = 256 = 16 q-rows x 16 e-lanes
// ---------------------------------------------------------------------------
__global__ __launch_bounds__(256) void k_attnout(const float* __restrict__ Qm,
                                                 const float* __restrict__ Km,
                                                 const float* __restrict__ Vm,
                                                 const float* __restrict__ invc,
                                                 float* __restrict__ AO) {
    int hb = blockIdx.y;
    int h = hb >> 2;
    int b = hb & 3;
    int q0 = blockIdx.x * 16;
    int tid = threadIdx.x;
    int qi = tid >> 4, ei = tid & 15;
    size_t base = (size_t)b * T_SEQ;

    __shared__ float Qt[16][17], Kt[16][17], Vt[16][17], Wt[16][17];
    Qt[qi][ei] = Qm[(base + q0 + qi) * DMODEL + h * EHEAD + ei];
    __syncthreads();

    float acc = 0.f;
    int ntiles = blockIdx.x + 1;
    for (int kt = 0; kt < ntiles; ++kt) {
        int k0 = kt * 16;
        Kt[qi][ei] = Km[(base + k0 + qi) * DMODEL + h * EHEAD + ei];
        Vt[qi][ei] = Vm[(base + k0 + qi) * DMODEL + h * EHEAD + ei];
        __syncthreads();
        int kcol = k0 + ei;
        float s = 0.f;
#pragma unroll
        for (int e = 0; e < EHEAD; ++e) s += Qt[qi][e] * Kt[ei][e];
        float w = 0.f;
        if (kcol <= q0 + qi)
            w = __expf(s * RSQRT_T) * invc[(size_t)hb * T_SEQ + kcol];
        Wt[qi][ei] = w;
        __syncthreads();
#pragma unroll
        for (int kk = 0; kk < 16; ++kk) acc += Wt[qi][kk] * Vt[kk][ei];
        __syncthreads();
    }
    AO[(base + q0 + qi) * DMODEL + h * EHEAD + ei] = acc;
}

// ---------------------------------------------------------------------------
// K5: fused FF: out = relu(AO@W1 + b1)@W2 + b2 + xpe
// block = 256 handles 16 rows; ff1 tile (16 x 512) kept in LDS
// ---------------------------------------------------------------------------
__global__ __launch_bounds__(256) void k_ff(const float* __restrict__ AO,
                                            const float* __restrict__ W1,
                                            const float* __restrict__ b1,
                                            const float* __restrict__ W2,
                                            const float* __restrict__ b2,
                                            const float* __restrict__ xpe,
                                            float* __restrict__ out) {
    __shared__ float At[16][DMODEL + 1];
    __shared__ float F[16][DFF + 1];
    int row0 = blockIdx.x * 16;
    int tid = threadIdx.x;
    for (int idx = tid; idx < 16 * DMODEL; idx += 256) {
        int r = idx >> 7, k = idx & 127;
        At[r][k] = AO[(size_t)(row0 + r) * DMODEL + k];
    }
    __syncthreads();
    int lcol = tid & 127;
    int rg = (tid >> 7) * 8;
    // ff1 = relu(At @ W1 + b1), 16x512
    for (int cc = 0; cc < 4; ++cc) {
        int col = cc * 128 + lcol;
        float acc[8];
#pragma unroll
        for (int r = 0; r < 8; ++r) acc[r] = 0.f;
        for (int k = 0; k < DMODEL; ++k) {
            float w = W1[(size_t)k * DFF + col];
#pragma unroll
            for (int r = 0; r < 8; ++r) acc[r] += At[rg + r][k] * w;
        }
        float b = b1[col];
#pragma unroll
        for (int r = 0; r < 8; ++r) F[rg + r][col] = fmaxf(acc[r] + b, 0.f);
    }
    __syncthreads();
    // ff2 = F @ W2 + b2 + xpe
    float acc2[8];
#pragma unroll
    for (int r = 0; r < 8; ++r) acc2[r] = 0.f;
    for (int k = 0; k < DFF; ++k) {
        float w = W2[(size_t)k * DMODEL + lcol];
#pragma unroll
        for (int r = 0; r < 8; ++r) acc2[r] += F[rg + r][k] * w;
    }
    float b = b2[lcol];
#pragma unroll
    for (int r = 0; r < 8; ++r) {
        int row = row0 + rg + r;
        out[(size_t)row * DMODEL + lcol] =
            acc2[r] + b + xpe[(size_t)row * DMODEL + lcol];
    }
}

// ---------------------------------------------------------------------------
extern "C" void kernel_launch(void* const* d_in, const int* in_sizes, int n_in,
                              void* d_out, int out_size, void* d_ws, size_t ws_size,
                              hipStream_t stream) {
    const float* x  = (const float*)d_in[0];
    const float* WQ = (const float*)d_in[1];
    const float* WK = (const float*)d_in[2];
    const float* WV = (const float*)d_in[3];
    const float* W1 = (const float*)d_in[4];
    const float* b1 = (const float*)d_in[5];
    const float* W2 = (const float*)d_in[6];
    const float* b2 = (const float*)d_in[7];
    float* out = (float*)d_out;
    float* ws = (float*)d_ws;

    const size_t NTD = (size_t)BATCH * T_SEQ * DMODEL;  // 1048576
    float* xpe  = ws;
    float* Qb   = ws + NTD;
    float* Kb   = ws + 2 * NTD;
    float* Vb   = ws + 3 * NTD;
    float* invc = ws + 4 * NTD;                      // H*B*T = 65536
    float* AO   = ws + 4 * NTD + (size_t)NHEAD * BATCH * T_SEQ;

    k_pe<<<dim3(NTD / 256), dim3(256), 0, stream>>>(x, xpe);

    k_gemm<DMODEL, DMODEL, false><<<dim3(512, 1), dim3(256), 0, stream>>>(
        xpe, WQ, nullptr, nullptr, Qb);
    k_gemm<DMODEL, DMODEL, false><<<dim3(512, 1), dim3(256), 0, stream>>>(
        xpe, WK, nullptr, nullptr, Kb);
    k_gemm<DMODEL, DMODEL, false><<<dim3(512, 1), dim3(256), 0, stream>>>(
        xpe, WV, nullptr, nullptr, Vb);

    k_colsum<<<dim3(T_SEQ / 256, NHEAD * BATCH), dim3(256), 0, stream>>>(
        Qb, Kb, invc);

    k_attnout<<<dim3(T_SEQ / 16, NHEAD * BATCH), dim3(256), 0, stream>>>(
        Qb, Kb, Vb, invc, AO);

    k_ff<<<dim3(512), dim3(256), 0, stream>>>(AO, W1, b1, W2, b2, xpe, out);
}

// Round 2
// 244.699 us; speedup vs baseline: 2.9716x; 2.9716x over previous
//
#include <hip/hip_runtime.h>
#include <math.h>
#include <stdint.h>

#define T_SEQ 2048
#define BATCH 4
#define DMODEL 128
#define DFF 512
#define NHEAD 8
#define EHEAD 16

// 1/sqrt(2048)
#define RSQRT_T 0.022097086912079608f

typedef __attribute__((ext_vector_type(8))) short bf16x8;
typedef __attribute__((ext_vector_type(4))) short bf16x4;
typedef __attribute__((ext_vector_type(4))) float f32x4;

__device__ __forceinline__ short f2bf(float f) {
    uint32_t u = __float_as_uint(f);
    u = u + 0x7FFF + ((u >> 16) & 1);
    return (short)(u >> 16);
}

// ---------------------------------------------------------------------------
// K1: xpe = x + positional_encoding
// ---------------------------------------------------------------------------
__global__ __launch_bounds__(256) void k_pe(const float* __restrict__ x,
                                            float* __restrict__ xpe) {
    int idx = blockIdx.x * 256 + threadIdx.x;       // over B*T*D = 1M
    int f = idx & (DMODEL - 1);
    int t = (idx >> 7) & (T_SEQ - 1);
    float dv = __expf(-(float)(f & ~1) * (9.210340371976184f / 128.0f));
    float ang = (float)t * dv;
    float pe = (f & 1) ? cosf(ang) : sinf(ang);
    xpe[idx] = x[idx] + pe;
}

// ---------------------------------------------------------------------------
// K2: QKV projection GEMM, 8192x128 @ 128x128, bf16 epilogues.
// EPI 0: dst[hb][t][16] bf16 = acc*scale (head-major, Q prescaled by rsqrtT)
// EPI 1: dst[hb][16][t] bf16 (e-major transposed, for V)
// block = 256 handles 16 rows x 128 cols; grid = 512
// ---------------------------------------------------------------------------
template <int EPI>
__global__ __launch_bounds__(256) void k_gemm_qkv(const float* __restrict__ A,
                                                  const float* __restrict__ W,
                                                  short* __restrict__ dst,
                                                  float scale) {
    __shared__ float At[16][DMODEL + 1];
    int row0 = blockIdx.x * 16;
    for (int idx = threadIdx.x; idx < 16 * DMODEL; idx += 256) {
        int r = idx >> 7, k = idx & 127;
        At[r][k] = A[(size_t)(row0 + r) * DMODEL + k];
    }
    __syncthreads();
    int col = threadIdx.x & 127;
    int rg = (threadIdx.x >> 7) * 8;
    float acc[8];
#pragma unroll
    for (int r = 0; r < 8; ++r) acc[r] = 0.f;
    for (int k = 0; k < DMODEL; ++k) {
        float w = W[(size_t)k * DMODEL + col];
#pragma unroll
        for (int r = 0; r < 8; ++r) acc[r] += At[rg + r][k] * w;
    }
    int h = col >> 4, e = col & 15;
#pragma unroll
    for (int r = 0; r < 8; ++r) {
        int row = row0 + rg + r;
        int b = row >> 11, t = row & (T_SEQ - 1);
        int hb = h * BATCH + b;
        if (EPI == 0) {
            dst[(hb * T_SEQ + t) * EHEAD + e] = f2bf(acc[r] * scale);
        } else {
            dst[(hb * EHEAD + e) * T_SEQ + t] = f2bf(acc[r]);
        }
    }
}

// ---------------------------------------------------------------------------
// K3: column-softmax denominators via MFMA.
// invc[hb][k] = 1 / sum_{q>=k} exp(S[q,k]); S has scale folded into Qh.
// grid = (32 kblocks, 32 hb), block = 256 (4 waves, one 16-col k-tile each)
// ---------------------------------------------------------------------------
__global__ __launch_bounds__(256) void k_colsum_mfma(const short* __restrict__ Qh,
                                                     const short* __restrict__ Kh,
                                                     float* __restrict__ invc) {
    int hb = blockIdx.y;
    int wave = threadIdx.x >> 6;
    int lane = threadIdx.x & 63;
    int g = lane >> 4, c = lane & 15;
    int kt = blockIdx.x * 4 + wave;
    int k0 = kt * 16;

    // B-frag: B[m=8g+j][col=c] = K[k0+c][e=8g+j]  (e>=16 -> zero pad)
    bf16x8 kf = {0, 0, 0, 0, 0, 0, 0, 0};
    if (g < 2)
        kf = *(const bf16x8*)(Kh + (hb * T_SEQ + k0 + c) * EHEAD + 8 * g);

    float csum = 0.f;
    for (int q0 = k0; q0 < T_SEQ; q0 += 16) {
        bf16x8 qf = {0, 0, 0, 0, 0, 0, 0, 0};
        if (g < 2)
            qf = *(const bf16x8*)(Qh + (hb * T_SEQ + q0 + c) * EHEAD + 8 * g);
        f32x4 z = {0.f, 0.f, 0.f, 0.f};
        // D[row=4g+t = q-in-tile][col=c = k-in-tile]
        f32x4 s = __builtin_amdgcn_mfma_f32_16x16x32_bf16(qf, kf, z, 0, 0, 0);
#pragma unroll
        for (int t = 0; t < 4; ++t) {
            int q = q0 + 4 * g + t;
            int k = k0 + c;
            csum += (q >= k) ? __expf(s[t]) : 0.f;
        }
    }
    csum += __shfl_xor(csum, 16);
    csum += __shfl_xor(csum, 32);
    if (lane < 16) invc[hb * T_SEQ + k0 + lane] = 1.0f / csum;
}

// ---------------------------------------------------------------------------
// K4: attention output via MFMA, swapped-operand chaining.
// AO[b][q][h*16+e] = sum_{k<=q} exp(S[q,k])*invc[k] * V[k][e]
// grid = (32 qblocks reversed, 32 hb), block = 256 (4 waves, 16 q-rows each)
// ---------------------------------------------------------------------------
__global__ __launch_bounds__(256) void k_attn_mfma(const short* __restrict__ Qh,
                                                   const short* __restrict__ Kh,
                                                   const short* __restrict__ Vt,
                                                   const float* __restrict__ invc,
                                                   float* __restrict__ AO) {
    int hb = blockIdx.y;
    int h = hb >> 2, b = hb & 3;
    int qb = gridDim.x - 1 - blockIdx.x;   // longest blocks dispatched first
    int wave = threadIdx.x >> 6;
    int lane = threadIdx.x & 63;
    int g = lane >> 4, c = lane & 15;
    int qt = qb * 4 + wave;
    int q0 = qt * 16;
    int q = q0 + c;                         // this lane's query column

    // Q B-frag: B[m=8g+j][col=c] = Q[q0+c][e=8g+j]
    bf16x8 qf = {0, 0, 0, 0, 0, 0, 0, 0};
    if (g < 2)
        qf = *(const bf16x8*)(Qh + (hb * T_SEQ + q0 + c) * EHEAD + 8 * g);

    const short* vbase = Vt + (hb * EHEAD + c) * T_SEQ;
    const float* ivbase = invc + hb * T_SEQ;

    f32x4 acc = {0.f, 0.f, 0.f, 0.f};
    f32x4 z = {0.f, 0.f, 0.f, 0.f};

    for (int k0 = 0; k0 <= q0; k0 += 32) {
        // ---- QK^T for two 16-k subtiles (swapped: A=K, B=Q) ----
        bf16x8 kf0 = {0, 0, 0, 0, 0, 0, 0, 0};
        bf16x8 kf1 = {0, 0, 0, 0, 0, 0, 0, 0};
        if (g < 2) {
            kf0 = *(const bf16x8*)(Kh + (hb * T_SEQ + k0 + c) * EHEAD + 8 * g);
            kf1 = *(const bf16x8*)(Kh + (hb * T_SEQ + k0 + 16 + c) * EHEAD + 8 * g);
        }
        // D[row=4g+t = k-in-subtile][col=c = q-in-tile] -> lane holds S[q][k0+4g+t]
        f32x4 s0 = __builtin_amdgcn_mfma_f32_16x16x32_bf16(kf0, qf, z, 0, 0, 0);
        f32x4 s1 = __builtin_amdgcn_mfma_f32_16x16x32_bf16(kf1, qf, z, 0, 0, 0);

        f32x4 iv0 = *(const f32x4*)(ivbase + k0 + 4 * g);
        f32x4 iv1 = *(const f32x4*)(ivbase + k0 + 16 + 4 * g);

        // ---- weights: w = exp(S)*invc[k], causal-masked ----
        bf16x8 a8;
#pragma unroll
        for (int t = 0; t < 4; ++t) {
            int k = k0 + 4 * g + t;
            float w = (k <= q) ? __expf(s0[t]) * iv0[t] : 0.f;
            a8[t] = f2bf(w);
        }
#pragma unroll
        for (int t = 0; t < 4; ++t) {
            int k = k0 + 16 + 4 * g + t;
            float w = (k <= q) ? __expf(s1[t]) * iv1[t] : 0.f;
            a8[4 + t] = f2bf(w);
        }

        // ---- V B-frag with permuted k (sigma): slots j=0..3 -> k0+4g+j,
        //      slots j=4..7 -> k0+16+4g+(j-4) ----
        bf16x4 v0 = *(const bf16x4*)(vbase + k0 + 4 * g);
        bf16x4 v1 = *(const bf16x4*)(vbase + k0 + 16 + 4 * g);
        bf16x8 vf;
#pragma unroll
        for (int t = 0; t < 4; ++t) { vf[t] = v0[t]; vf[4 + t] = v1[t]; }

        // ---- PV accumulate: A-frag row = q (lane c), m-slots = permuted k ----
        acc = __builtin_amdgcn_mfma_f32_16x16x32_bf16(a8, vf, acc, 0, 0, 0);
    }

    // acc: lane holds O[q0+4g+t][e=c]
#pragma unroll
    for (int t = 0; t < 4; ++t) {
        int qrow = q0 + 4 * g + t;
        AO[(size_t)(b * T_SEQ + qrow) * DMODEL + h * EHEAD + c] = acc[t];
    }
}

// ---------------------------------------------------------------------------
// K5: fused FF: out = relu(AO@W1 + b1)@W2 + b2 + xpe
// ---------------------------------------------------------------------------
__global__ __launch_bounds__(256) void k_ff(const float* __restrict__ AO,
                                            const float* __restrict__ W1,
                                            const float* __restrict__ b1,
                                            const float* __restrict__ W2,
                                            const float* __restrict__ b2,
                                            const float* __restrict__ xpe,
                                            float* __restrict__ out) {
    __shared__ float At[16][DMODEL + 1];
    __shared__ float F[16][DFF + 1];
    int row0 = blockIdx.x * 16;
    int tid = threadIdx.x;
    for (int idx = tid; idx < 16 * DMODEL; idx += 256) {
        int r = idx >> 7, k = idx & 127;
        At[r][k] = AO[(size_t)(row0 + r) * DMODEL + k];
    }
    __syncthreads();
    int lcol = tid & 127;
    int rg = (tid >> 7) * 8;
    for (int cc = 0; cc < 4; ++cc) {
        int col = cc * 128 + lcol;
        float acc[8];
#pragma unroll
        for (int r = 0; r < 8; ++r) acc[r] = 0.f;
        for (int k = 0; k < DMODEL; ++k) {
            float w = W1[(size_t)k * DFF + col];
#pragma unroll
            for (int r = 0; r < 8; ++r) acc[r] += At[rg + r][k] * w;
        }
        float b = b1[col];
#pragma unroll
        for (int r = 0; r < 8; ++r) F[rg + r][col] = fmaxf(acc[r] + b, 0.f);
    }
    __syncthreads();
    float acc2[8];
#pragma unroll
    for (int r = 0; r < 8; ++r) acc2[r] = 0.f;
    for (int k = 0; k < DFF; ++k) {
        float w = W2[(size_t)k * DMODEL + lcol];
#pragma unroll
        for (int r = 0; r < 8; ++r) acc2[r] += F[rg + r][k] * w;
    }
    float b = b2[lcol];
#pragma unroll
    for (int r = 0; r < 8; ++r) {
        int row = row0 + rg + r;
        out[(size_t)row * DMODEL + lcol] =
            acc2[r] + b + xpe[(size_t)row * DMODEL + lcol];
    }
}

// ---------------------------------------------------------------------------
extern "C" void kernel_launch(void* const* d_in, const int* in_sizes, int n_in,
                              void* d_out, int out_size, void* d_ws, size_t ws_size,
                              hipStream_t stream) {
    const float* x  = (const float*)d_in[0];
    const float* WQ = (const float*)d_in[1];
    const float* WK = (const float*)d_in[2];
    const float* WV = (const float*)d_in[3];
    const float* W1 = (const float*)d_in[4];
    const float* b1 = (const float*)d_in[5];
    const float* W2 = (const float*)d_in[6];
    const float* b2 = (const float*)d_in[7];
    float* out = (float*)d_out;

    const size_t NTD = (size_t)BATCH * T_SEQ * DMODEL;  // 1048576
    float* xpe  = (float*)d_ws;
    float* AO   = xpe + NTD;
    float* invc = AO + NTD;                              // 65536 floats
    short* Qh   = (short*)(invc + (size_t)NHEAD * BATCH * T_SEQ);
    short* Kh   = Qh + NTD;
    short* Vt   = Kh + NTD;

    k_pe<<<dim3(NTD / 256), dim3(256), 0, stream>>>(x, xpe);

    k_gemm_qkv<0><<<dim3(512), dim3(256), 0, stream>>>(xpe, WQ, Qh, RSQRT_T);
    k_gemm_qkv<0><<<dim3(512), dim3(256), 0, stream>>>(xpe, WK, Kh, 1.0f);
    k_gemm_qkv<1><<<dim3(512), dim3(256), 0, stream>>>(xpe, WV, Vt, 1.0f);

    k_colsum_mfma<<<dim3(32, 32), dim3(256), 0, stream>>>(Qh, Kh, invc);

    k_attn_mfma<<<dim3(32, 32), dim3(256), 0, stream>>>(Qh, Kh, Vt, invc, AO);

    k_ff<<<dim3(512), dim3(256), 0, stream>>>(AO, W1, b1, W2, b2, xpe, out);
}

// Round 3
// 138.181 us; speedup vs baseline: 5.2623x; 1.7709x over previous
//
#include <hip/hip_runtime.h>
#include <math.h>
#include <stdint.h>

#define T_SEQ 2048
#define BATCH 4
#define DMODEL 128
#define DFF 512
#define NHEAD 8
#define EHEAD 16

#define RSQRT_T 0.022097086912079608f
#define QSCALE (0.022097086912079608f * 1.4426950408889634f)   // fold log2(e): use exp2

typedef __attribute__((ext_vector_type(8))) short bf16x8;
typedef __attribute__((ext_vector_type(4))) short bf16x4;
typedef __attribute__((ext_vector_type(4))) float f32x4;

__device__ __forceinline__ short f2bf(float f) {            // RNE
    uint32_t u = __float_as_uint(f);
    u = u + 0x7FFF + ((u >> 16) & 1);
    return (short)(u >> 16);
}
__device__ __forceinline__ short bftrunc(float f) {         // truncate (cheap)
    return (short)(__float_as_uint(f) >> 16);
}
__device__ __forceinline__ float bf2f(short s) {
    return __uint_as_float(((uint32_t)(unsigned short)s) << 16);
}

// ---------------------------------------------------------------------------
// K0: xpe = x + PE (fp32 + bf16 copies); transpose+convert all weights to bf16
// ---------------------------------------------------------------------------
__global__ __launch_bounds__(256) void k_pre(const float* __restrict__ x,
                                             const float* __restrict__ WQ,
                                             const float* __restrict__ WK,
                                             const float* __restrict__ WV,
                                             const float* __restrict__ W1,
                                             const float* __restrict__ W2,
                                             float* __restrict__ xpe,
                                             short* __restrict__ xpe16,
                                             short* __restrict__ Wqkvt,
                                             short* __restrict__ W1t,
                                             short* __restrict__ W2t) {
    int bid = blockIdx.x;
    int tid = threadIdx.x;
    if (bid < 4096) {                       // PE over B*T*D = 1M
        int idx = bid * 256 + tid;
        int f = idx & (DMODEL - 1);
        int t = (idx >> 7) & (T_SEQ - 1);
        float dv = __expf(-(float)(f & ~1) * (9.210340371976184f / 128.0f));
        float ang = (float)t * dv;
        float pe = (f & 1) ? __cosf(ang) : __sinf(ang);
        float v = x[idx] + pe;
        xpe[idx] = v;
        xpe16[idx] = f2bf(v);
    } else if (bid < 4288) {                // WQ/WK/WV -> [n][k] bf16
        int m = (bid - 4096) >> 6;
        int o = ((bid - 4096) & 63) * 256 + tid;      // 0..16383
        int n = o >> 7, k = o & 127;
        const float* W = (m == 0) ? WQ : (m == 1) ? WK : WV;
        Wqkvt[m * 16384 + o] = f2bf(W[k * 128 + n]);
    } else if (bid < 4544) {                // W1 [128][512] -> W1t [512][128]
        int o = (bid - 4288) * 256 + tid;   // 0..65535
        int n = o >> 7, k = o & 127;
        W1t[o] = f2bf(W1[k * 512 + n]);
    } else {                                // W2 [512][128] -> W2t [128][512]
        int o = (bid - 4544) * 256 + tid;   // 0..65535
        int n = o >> 9, k = o & 511;
        W2t[o] = f2bf(W2[k * 128 + n]);
    }
}

// ---------------------------------------------------------------------------
// K1: QKV projection: bf16 MFMA GEMM, W in registers (Wt[n][k] bf16).
// z=0: Qh[hb][t][16] *= QSCALE; z=1: Kh[hb][t][16]; z=2: Vs[hb][e][T]
// block 256 (4 waves x 16 rows = 64 rows), grid (128, 3)
// ---------------------------------------------------------------------------
__global__ __launch_bounds__(256) void k_qkv(const short* __restrict__ xpe16,
                                             const short* __restrict__ Wqkvt,
                                             short* __restrict__ Qh,
                                             short* __restrict__ Kh,
                                             short* __restrict__ Vs) {
    int z = blockIdx.y;
    const short* Wt = Wqkvt + z * 16384;
    int wave = threadIdx.x >> 6, lane = threadIdx.x & 63;
    int g = lane >> 4, c = lane & 15;
    int row0 = blockIdx.x * 64 + wave * 16;

    bf16x8 wf[8][4];
#pragma unroll
    for (int nt = 0; nt < 8; ++nt)
#pragma unroll
        for (int kk = 0; kk < 4; ++kk)
            wf[nt][kk] = *(const bf16x8*)(Wt + (nt * 16 + c) * 128 + kk * 32 + 8 * g);

    bf16x8 af[4];
#pragma unroll
    for (int kk = 0; kk < 4; ++kk)
        af[kk] = *(const bf16x8*)(xpe16 + (size_t)(row0 + c) * 128 + kk * 32 + 8 * g);

    f32x4 acc[8];
#pragma unroll
    for (int nt = 0; nt < 8; ++nt) acc[nt] = (f32x4){0.f, 0.f, 0.f, 0.f};
#pragma unroll
    for (int kk = 0; kk < 4; ++kk)
#pragma unroll
        for (int nt = 0; nt < 8; ++nt)
            acc[nt] = __builtin_amdgcn_mfma_f32_16x16x32_bf16(af[kk], wf[nt][kk], acc[nt], 0, 0, 0);

    int b = row0 >> 11;
    int t0 = (row0 & (T_SEQ - 1)) + 4 * g;
    if (z < 2) {
        short* dst = (z == 0) ? Qh : Kh;
        float sc = (z == 0) ? QSCALE : 1.0f;
#pragma unroll
        for (int nt = 0; nt < 8; ++nt) {
            int hb = nt * 4 + b;
#pragma unroll
            for (int r = 0; r < 4; ++r)
                dst[(size_t)(hb * T_SEQ + t0 + r) * 16 + c] = f2bf(acc[nt][r] * sc);
        }
    } else {
#pragma unroll
        for (int nt = 0; nt < 8; ++nt) {
            int hb = nt * 4 + b;
            bf16x4 v;
#pragma unroll
            for (int r = 0; r < 4; ++r) v[r] = f2bf(acc[nt][r]);
            *(bf16x4*)(Vs + (size_t)(hb * 16 + c) * T_SEQ + t0) = v;
        }
    }
}

// ---------------------------------------------------------------------------
// K2: column-softmax denominators + pre-scale V in place:
// Vs[hb][e][k] *= 1 / sum_{q>=k} exp2(S'[q,k])
// grid (16 kchunks: 0 = longest first, 32 hb), block 512 (8 waves x 16 cols)
// ---------------------------------------------------------------------------
__global__ __launch_bounds__(512) void k_colsum(const short* __restrict__ Qh,
                                                const short* __restrict__ Kh,
                                                short* __restrict__ Vs) {
    int hb = blockIdx.y;
    int wave = threadIdx.x >> 6, lane = threadIdx.x & 63;
    int g = lane >> 4, c = lane & 15;
    int k0 = blockIdx.x * 128 + wave * 16;
    const int hbT = hb * T_SEQ;
    const f32x4 z = {0.f, 0.f, 0.f, 0.f};

    bf16x8 kf = {0, 0, 0, 0, 0, 0, 0, 0};
    if (g < 2) kf = *(const bf16x8*)(Kh + (size_t)(hbT + k0 + c) * 16 + 8 * g);

    float csum = 0.f;
    {   // diagonal tile (masked): q = k0+4g+r, k = k0+c
        bf16x8 qf = {0, 0, 0, 0, 0, 0, 0, 0};
        if (g < 2) qf = *(const bf16x8*)(Qh + (size_t)(hbT + k0 + c) * 16 + 8 * g);
        f32x4 s = __builtin_amdgcn_mfma_f32_16x16x32_bf16(qf, kf, z, 0, 0, 0);
#pragma unroll
        for (int r = 0; r < 4; ++r)
            csum += (4 * g + r >= c) ? exp2f(s[r]) : 0.f;
    }
    for (int q0 = k0 + 16; q0 < T_SEQ; q0 += 16) {
        bf16x8 qf = {0, 0, 0, 0, 0, 0, 0, 0};
        if (g < 2) qf = *(const bf16x8*)(Qh + (size_t)(hbT + q0 + c) * 16 + 8 * g);
        f32x4 s = __builtin_amdgcn_mfma_f32_16x16x32_bf16(qf, kf, z, 0, 0, 0);
#pragma unroll
        for (int r = 0; r < 4; ++r) csum += exp2f(s[r]);
    }
    csum += __shfl_xor(csum, 16);
    csum += __shfl_xor(csum, 32);
    float inv = 1.0f / csum;
#pragma unroll
    for (int j = 0; j < 4; ++j) {
        size_t idx = (size_t)(hb * 16 + g * 4 + j) * T_SEQ + k0 + c;
        Vs[idx] = f2bf(bf2f(Vs[idx]) * inv);
    }
}

// ---------------------------------------------------------------------------
// K3: attention output. O[q] = sum_{k<=q} exp2(S')*Vs (V pre-scaled).
// block 512 = 8 waves x 16 q-rows; LDS double-buffered K/V tiles (32 k wide).
// V tile stored XOR-swizzled for conflict-free b64 reads.
// ---------------------------------------------------------------------------
__global__ __launch_bounds__(512) void k_attn(const short* __restrict__ Qh,
                                              const short* __restrict__ Kh,
                                              const short* __restrict__ Vs,
                                              short* __restrict__ AObf) {
    __shared__ short Kl[2][512];
    __shared__ short Vl[2][512];
    int hb = blockIdx.y, h = hb >> 2, b = hb & 3;
    int qc = (int)gridDim.x - 1 - (int)blockIdx.x;      // longest first
    int tid = threadIdx.x;
    int wave = tid >> 6, lane = tid & 63, g = lane >> 4, c = lane & 15;
    int q0 = qc * 128 + wave * 16;
    const int hbT = hb * T_SEQ;

    bf16x8 qf = {0, 0, 0, 0, 0, 0, 0, 0};
    if (g < 2) qf = *(const bf16x8*)(Qh + (size_t)(hbT + q0 + c) * 16 + 8 * g);

    int nW = (q0 >> 5) + 1;          // tiles this wave needs (last is masked)
    int nBlk = qc * 4 + 4;           // tiles staged by the block

    // staging sources (waves 0/1): K linear [32][16]; V swizzled 16B units
    int vE = lane >> 2;
    int vG = (lane & 3) ^ (vE & 3);
    const short* Ksrc0 = Kh + (size_t)hbT * 16 + lane * 8;
    const short* Vsrc0 = Vs + (size_t)(hb * 16 + vE) * T_SEQ + 8 * vG;

    // V read offsets (shorts): row c, k-offset 4g and 16+4g, swizzled units
    int vr0 = (c * 4 + ((g >> 1) ^ (c & 3))) * 8 + (g & 1) * 4;
    int vr1 = (c * 4 + (((g >> 1) + 2) ^ (c & 3))) * 8 + (g & 1) * 4;

    if (wave == 0) *(bf16x8*)&Kl[0][lane * 8] = *(const bf16x8*)(Ksrc0);
    else if (wave == 1) *(bf16x8*)&Vl[0][lane * 8] = *(const bf16x8*)(Vsrc0);
    __syncthreads();

    f32x4 acc = {0.f, 0.f, 0.f, 0.f};
    const f32x4 z = {0.f, 0.f, 0.f, 0.f};
    int q = q0 + c;

    for (int it = 0; it < nBlk; ++it) {
        int buf = it & 1;
        // T14: issue next-tile loads early, ds_write after compute
        bf16x8 stv;
        bool doStage = (it + 1 < nBlk) && (wave < 2);
        if (doStage) {
            int k0n = (it + 1) * 32;
            stv = (wave == 0) ? *(const bf16x8*)(Ksrc0 + k0n * 16)
                              : *(const bf16x8*)(Vsrc0 + k0n);
        }
        if (it < nW) {
            bf16x8 kf0 = {0, 0, 0, 0, 0, 0, 0, 0};
            bf16x8 kf1 = {0, 0, 0, 0, 0, 0, 0, 0};
            if (g < 2) {
                kf0 = *(const bf16x8*)&Kl[buf][c * 16 + g * 8];
                kf1 = *(const bf16x8*)&Kl[buf][256 + c * 16 + g * 8];
            }
            f32x4 s0 = __builtin_amdgcn_mfma_f32_16x16x32_bf16(kf0, qf, z, 0, 0, 0);
            f32x4 s1 = __builtin_amdgcn_mfma_f32_16x16x32_bf16(kf1, qf, z, 0, 0, 0);
            bf16x8 a8;
            if (it < nW - 1) {          // full tile: no masking
#pragma unroll
                for (int t = 0; t < 4; ++t) a8[t] = bftrunc(exp2f(s0[t]));
#pragma unroll
                for (int t = 0; t < 4; ++t) a8[4 + t] = bftrunc(exp2f(s1[t]));
            } else {                    // diagonal tile
                int k0 = it * 32;
#pragma unroll
                for (int t = 0; t < 4; ++t) {
                    int k = k0 + 4 * g + t;
                    a8[t] = (k <= q) ? bftrunc(exp2f(s0[t])) : (short)0;
                }
#pragma unroll
                for (int t = 0; t < 4; ++t) {
                    int k = k0 + 16 + 4 * g + t;
                    a8[4 + t] = (k <= q) ? bftrunc(exp2f(s1[t])) : (short)0;
                }
            }
            bf16x4 v0 = *(const bf16x4*)&Vl[buf][vr0];
            bf16x4 v1 = *(const bf16x4*)&Vl[buf][vr1];
            bf16x8 vf;
#pragma unroll
            for (int t = 0; t < 4; ++t) { vf[t] = v0[t]; vf[4 + t] = v1[t]; }
            acc = __builtin_amdgcn_mfma_f32_16x16x32_bf16(a8, vf, acc, 0, 0, 0);
        }
        if (doStage) {
            if (wave == 0) *(bf16x8*)&Kl[buf ^ 1][lane * 8] = stv;
            else           *(bf16x8*)&Vl[buf ^ 1][lane * 8] = stv;
        }
        __syncthreads();
    }
#pragma unroll
    for (int r = 0; r < 4; ++r)
        AObf[(size_t)(b * T_SEQ + q0 + 4 * g + r) * DMODEL + h * EHEAD + c] = f2bf(acc[r]);
}

// ---------------------------------------------------------------------------
// K4: ff1 = relu(AO @ W1 + b1) -> F bf16 [8192][512]. W1t[n][k] in registers.
// block 256 (4 waves x 16 rows), grid (128 rowstrips, 4 colchunks)
// ---------------------------------------------------------------------------
__global__ __launch_bounds__(256) void k_ff1(const short* __restrict__ AObf,
                                             const short* __restrict__ W1t,
                                             const float* __restrict__ b1,
                                             short* __restrict__ F) {
    int nc = blockIdx.y;
    int wave = threadIdx.x >> 6, lane = threadIdx.x & 63;
    int g = lane >> 4, c = lane & 15;
    int row0 = blockIdx.x * 64 + wave * 16;

    bf16x8 wf[8][4];
#pragma unroll
    for (int nt = 0; nt < 8; ++nt)
#pragma unroll
        for (int kk = 0; kk < 4; ++kk)
            wf[nt][kk] = *(const bf16x8*)(W1t + (nc * 128 + nt * 16 + c) * 128 + kk * 32 + 8 * g);

    bf16x8 af[4];
#pragma unroll
    for (int kk = 0; kk < 4; ++kk)
        af[kk] = *(const bf16x8*)(AObf + (size_t)(row0 + c) * 128 + kk * 32 + 8 * g);

    f32x4 acc[8];
#pragma unroll
    for (int nt = 0; nt < 8; ++nt) acc[nt] = (f32x4){0.f, 0.f, 0.f, 0.f};
#pragma unroll
    for (int kk = 0; kk < 4; ++kk)
#pragma unroll
        for (int nt = 0; nt < 8; ++nt)
            acc[nt] = __builtin_amdgcn_mfma_f32_16x16x32_bf16(af[kk], wf[nt][kk], acc[nt], 0, 0, 0);

#pragma unroll
    for (int nt = 0; nt < 8; ++nt) {
        int col = nc * 128 + nt * 16 + c;
        float bb = b1[col];
#pragma unroll
        for (int r = 0; r < 4; ++r)
            F[(size_t)(row0 + 4 * g + r) * DFF + col] = f2bf(fmaxf(acc[nt][r] + bb, 0.f));
    }
}

// ---------------------------------------------------------------------------
// K5: out = F @ W2 + b2 + xpe. W2t[n][k=512] in registers (32-col groups).
// block 256 (4 waves x 16 rows), grid (128 rowstrips, 4 colgroups)
// ---------------------------------------------------------------------------
__global__ __launch_bounds__(256) void k_ff2(const short* __restrict__ F,
                                             const short* __restrict__ W2t,
                                             const float* __restrict__ b2,
                                             const float* __restrict__ xpe,
                                             float* __restrict__ out) {
    int ng = blockIdx.y;
    int wave = threadIdx.x >> 6, lane = threadIdx.x & 63;
    int g = lane >> 4, c = lane & 15;
    int row0 = blockIdx.x * 64 + wave * 16;

    bf16x8 wf[2][16];
#pragma unroll
    for (int nt = 0; nt < 2; ++nt)
#pragma unroll
        for (int kk = 0; kk < 16; ++kk)
            wf[nt][kk] = *(const bf16x8*)(W2t + (ng * 32 + nt * 16 + c) * 512 + kk * 32 + 8 * g);

    f32x4 acc[2];
    acc[0] = (f32x4){0.f, 0.f, 0.f, 0.f};
    acc[1] = (f32x4){0.f, 0.f, 0.f, 0.f};
#pragma unroll
    for (int kk = 0; kk < 16; ++kk) {
        bf16x8 a = *(const bf16x8*)(F + (size_t)(row0 + c) * 512 + kk * 32 + 8 * g);
        acc[0] = __builtin_amdgcn_mfma_f32_16x16x32_bf16(a, wf[0][kk], acc[0], 0, 0, 0);
        acc[1] = __builtin_amdgcn_mfma_f32_16x16x32_bf16(a, wf[1][kk], acc[1], 0, 0, 0);
    }
#pragma unroll
    for (int nt = 0; nt < 2; ++nt) {
        int col = ng * 32 + nt * 16 + c;
        float bb = b2[col];
#pragma unroll
        for (int r = 0; r < 4; ++r) {
            size_t o = (size_t)(row0 + 4 * g + r) * DMODEL + col;
            out[o] = acc[nt][r] + bb + xpe[o];
        }
    }
}

// ---------------------------------------------------------------------------
extern "C" void kernel_launch(void* const* d_in, const int* in_sizes, int n_in,
                              void* d_out, int out_size, void* d_ws, size_t ws_size,
                              hipStream_t stream) {
    const float* x  = (const float*)d_in[0];
    const float* WQ = (const float*)d_in[1];
    const float* WK = (const float*)d_in[2];
    const float* WV = (const float*)d_in[3];
    const float* W1 = (const float*)d_in[4];
    const float* b1 = (const float*)d_in[5];
    const float* W2 = (const float*)d_in[6];
    const float* b2 = (const float*)d_in[7];
    float* out = (float*)d_out;

    const size_t NTD = (size_t)BATCH * T_SEQ * DMODEL;   // 1048576
    float* xpe   = (float*)d_ws;
    short* sbase = (short*)(xpe + NTD);
    short* xpe16 = sbase;
    short* Qh    = xpe16 + NTD;
    short* Kh    = Qh + NTD;
    short* Vs    = Kh + NTD;
    short* AObf  = Vs + NTD;
    short* F     = AObf + NTD;            // 8192*512 = 4*NTD shorts
    short* Wqkvt = F + 4 * NTD;
    short* W1t   = Wqkvt + 3 * 16384;
    short* W2t   = W1t + 65536;

    k_pre<<<dim3(4800), dim3(256), 0, stream>>>(x, WQ, WK, WV, W1, W2,
                                                xpe, xpe16, Wqkvt, W1t, W2t);

    k_qkv<<<dim3(128, 3), dim3(256), 0, stream>>>(xpe16, Wqkvt, Qh, Kh, Vs);

    k_colsum<<<dim3(16, 32), dim3(512), 0, stream>>>(Qh, Kh, Vs);

    k_attn<<<dim3(16, 32), dim3(512), 0, stream>>>(Qh, Kh, Vs, AObf);

    k_ff1<<<dim3(128, 4), dim3(256), 0, stream>>>(AObf, W1t, b1, F);

    k_ff2<<<dim3(128, 4), dim3(256), 0, stream>>>(F, W2t, b2, xpe, out);
}